// Round 9
// baseline (89.518 us; speedup 1.0000x reference)
//
#include <hip/hip_runtime.h>

#define KS    7
#define RAD   3
#define TS    32            // tile is 32x32 output px
#define HALO  38            // TS + 2*RAD
#define NT    (HALO*HALO)   // 1444 staging sites
#define PITCH 43            // physical row stride in col-units (max swz(37)=41, +pad)
#define H     256
#define W     256
#define HWp   (H*W)

typedef __fp16    h2raw __attribute__((ext_vector_type(2)));
typedef _Float16  f16x2 __attribute__((ext_vector_type(2)));

// skew: spreads stride-2 reads across bank groups
__device__ __forceinline__ int swz(int c) { return c + (c >> 3); }

__device__ __forceinline__ unsigned pk(float a, float b) {
    h2raw h = __builtin_amdgcn_cvt_pkrtz(a, b);
    return __builtin_bit_cast(unsigned, h);
}
__device__ __forceinline__ f16x2 pkh(float a, float b) {
    return __builtin_bit_cast(f16x2, __builtin_amdgcn_cvt_pkrtz(a, b));
}

#if __has_builtin(__builtin_amdgcn_fdot2)
__device__ __forceinline__ float fdot2(f16x2 a, f16x2 b, float c) {
    return __builtin_amdgcn_fdot2(a, b, c, false);
}
#else
__device__ __forceinline__ float fdot2(f16x2 a, f16x2 b, float c) {
    return c + (float)a.x * (float)b.x + (float)a.y * (float)b.y;
}
#endif

__global__ __launch_bounds__(256, 2)
void bilateral_kernel(const float* __restrict__ in,      // [B][32][H][W]
                      const float* __restrict__ guide,   // [B][3][H][W]
                      const float* __restrict__ sigma_p, // [1]
                      float* __restrict__ out)           // [B][32][H][W]
{
    __shared__ uint2 gt[HALO * PITCH];   // guide: {x,y},{z,0} fp16 (8B/site)
    __shared__ uint4 dt[HALO * PITCH];   // input: 8ch fp16 (16B/site)

    const int tid = threadIdx.x;
    const int tx  = tid & 15;            // x-pair (0..15)
    const int ty  = tid >> 4;            // y-pair (0..15)
    const int x0  = blockIdx.x * TS;
    const int y0  = blockIdx.y * TS;
    const int b   = blockIdx.z >> 2;     // batch
    const int cg0 = (blockIdx.z & 3) * 8;

    const float* gb  = guide + (size_t)b * 3 * HWp;
    const float* inb = in    + ((size_t)b * 32 + cg0) * HWp;

    const float sigma = sigma_p[0];
    const float isig2 = 1.0f / (sigma * sigma);
    float lnT[KS];
#pragma unroll
    for (int i = 0; i < KS; ++i) {
        float r = (float)(i - RAD);
        lnT[i] = -0.5f * r * r * isig2;
    }

    // ---- stage: guide fp16 (uint2) + input 8ch fp16 (uint4), zero halo ----
#pragma unroll
    for (int it = 0; it < 6; ++it) {
        int idx = tid + it * 256;
        if (idx < NT) {
            int row = idx / HALO;
            int col = idx - row * HALO;
            int gy = y0 - RAD + row, gx = x0 - RAD + col;
            uint2 gv = make_uint2(0u, 0u);
            uint4 pv = make_uint4(0u, 0u, 0u, 0u);
            if (gy >= 0 && gy < H && gx >= 0 && gx < W) {
                int off = gy * W + gx;
                gv.x = pk(gb[off], gb[HWp + off]);
                gv.y = pk(gb[2 * HWp + off], 0.f);
                float v0 = inb[off],           v1 = inb[HWp + off];
                float v2 = inb[2 * HWp + off], v3 = inb[3 * HWp + off];
                float v4 = inb[4 * HWp + off], v5 = inb[5 * HWp + off];
                float v6 = inb[6 * HWp + off], v7 = inb[7 * HWp + off];
                pv.x = pk(v0, v1); pv.y = pk(v2, v3);
                pv.z = pk(v4, v5); pv.w = pk(v6, v7);
            }
            int a = row * PITCH + swz(col);
            gt[a] = gv;
            dt[a] = pv;
        }
    }
    __syncthreads();

    // ---- negated centers for the 2x2 pixels (halo row 2ty+3/+4, col 2tx+3/+4) ----
    f16x2 ncxy[4], ncz[4];
    {
#pragma unroll
        for (int p = 0; p < 4; ++p) {
            int r = 2 * ty + 3 + (p >> 1);
            int c = 2 * tx + 3 + (p & 1);
            uint2 cr = gt[r * PITCH + swz(c)];
            ncxy[p] = -__builtin_bit_cast(f16x2, cr.x);
            ncz[p]  = -__builtin_bit_cast(f16x2, cr.y);
        }
    }

    float nsum[4] = {0.f, 0.f, 0.f, 0.f};
    float acc[4][8];
#pragma unroll
    for (int p = 0; p < 4; ++p)
#pragma unroll
        for (int c = 0; c < 8; ++c) acc[p][c] = 0.f;

    f16x2 A[4][4];
#pragma unroll
    for (int p = 0; p < 4; ++p)
#pragma unroll
        for (int k = 0; k < 4; ++k) A[p][k] = (f16x2)0;

    // one tap for pixel p: window col k, log-spatial lnE
#define TAP(p, k, lnE) do {                                                  \
        f16x2 gxy = __builtin_bit_cast(f16x2, gq[k].x);                      \
        f16x2 gz  = __builtin_bit_cast(f16x2, gq[k].y);                      \
        f16x2 dxy = gxy + ncxy[p];                                           \
        f16x2 dz  = gz + ncz[p];                                             \
        float s = fdot2(dxy, dxy, fdot2(dz, dz, 0.f));                       \
        float w = __expf(fmaf(s, -0.5f, (lnE)));                             \
        nsum[p] += w;                                                        \
        f16x2 wh = pkh(w, w);                                                \
        A[p][0] = wh * __builtin_bit_cast(f16x2, rq[k].x) + A[p][0];         \
        A[p][1] = wh * __builtin_bit_cast(f16x2, rq[k].y) + A[p][1];         \
        A[p][2] = wh * __builtin_bit_cast(f16x2, rq[k].z) + A[p][2];         \
        A[p][3] = wh * __builtin_bit_cast(f16x2, rq[k].w) + A[p][3];         \
    } while (0)

    // ---- fused weight+apply: 8 window rows serve both y-pixels ----
#pragma unroll
    for (int i = 0; i < 8; ++i) {
        const int base = (2 * ty + i) * PITCH;
        uint2 gq[8];
        uint4 rq[8];
#pragma unroll
        for (int k = 0; k < 8; ++k) {
            int a = base + swz(2 * tx + k);
            gq[k] = gt[a];
            rq[k] = dt[a];
        }
#pragma unroll
        for (int dj = 0; dj < KS; ++dj) {
            if (i < 7) {                       // y-px0: tap row i
                const float lnE = lnT[i] + lnT[dj];
                TAP(0, dj, lnE);
                TAP(1, dj + 1, lnE);
            }
            if (i > 0) {                       // y-px1: tap row i-1
                const float lnE = lnT[i - 1] + lnT[dj];
                TAP(2, dj, lnE);
                TAP(3, dj + 1, lnE);
            }
        }
        if (i == 3 || i == 7) {                // bound fp16 chains at <=28 adds
#pragma unroll
            for (int p = 0; p < 4; ++p) {
#pragma unroll
                for (int k = 0; k < 4; ++k) {
                    acc[p][2 * k]     += (float)A[p][k].x;
                    acc[p][2 * k + 1] += (float)A[p][k].y;
                    A[p][k] = (f16x2)0;
                }
            }
        }
    }

    // ---- normalize + store (norm >= center weight = 1, never 0) ----
    float inv[4];
#pragma unroll
    for (int p = 0; p < 4; ++p) inv[p] = 1.f / nsum[p];
    const int X = x0 + 2 * tx, Y = y0 + 2 * ty;
    float* ob = out + ((size_t)b * 32 + cg0) * HWp + (size_t)Y * W + X;
#pragma unroll
    for (int c = 0; c < 8; ++c) {
        float2 s0, s1;
        s0.x = acc[0][c] * inv[0]; s0.y = acc[1][c] * inv[1];
        s1.x = acc[2][c] * inv[2]; s1.y = acc[3][c] * inv[3];
        *(float2*)(ob + (size_t)c * HWp)     = s0;
        *(float2*)(ob + (size_t)c * HWp + W) = s1;
    }
}

extern "C" void kernel_launch(void* const* d_in, const int* in_sizes, int n_in,
                              void* d_out, int out_size, void* d_ws, size_t ws_size,
                              hipStream_t stream) {
    const float* in    = (const float*)d_in[0];
    const float* guide = (const float*)d_in[1];
    const float* sigma = (const float*)d_in[2];
    float* out = (float*)d_out;
    dim3 grid(W / TS, H / TS, 2 * 4);   // z = batch*4 + channel-quarter
    bilateral_kernel<<<grid, dim3(256), 0, stream>>>(in, guide, sigma, out);
}

// Round 10
// 29.535 us; speedup vs baseline: 3.0310x; 3.0310x over previous
//
#include <hip/hip_runtime.h>

#define KS    7
#define RAD   3
#define TW    32            // tile width (output px)
#define TH    16            // tile height
#define HC    38            // TW + 2*RAD
#define HR    22            // TH + 2*RAD
#define NT    (HR*HC)       // 836 staging sites
#define PAIRS 21            // col-pairs per parity row (need 19, +2 pad for row bank shift)
#define H     256
#define W     256
#define HWp   (H*W)

typedef __fp16    h2raw __attribute__((ext_vector_type(2)));
typedef _Float16  f16x2 __attribute__((ext_vector_type(2)));

__device__ __forceinline__ unsigned pk(float a, float b) {
    h2raw h = __builtin_amdgcn_cvt_pkrtz(a, b);
    return __builtin_bit_cast(unsigned, h);
}
__device__ __forceinline__ f16x2 pkh(float a, float b) {
    return __builtin_bit_cast(f16x2, __builtin_amdgcn_cvt_pkrtz(a, b));
}

#if __has_builtin(__builtin_amdgcn_fdot2)
__device__ __forceinline__ float fdot2(f16x2 a, f16x2 b, float c) {
    return __builtin_amdgcn_fdot2(a, b, c, false);
}
#else
__device__ __forceinline__ float fdot2(f16x2 a, f16x2 b, float c) {
    return c + (float)a.x * (float)b.x + (float)a.y * (float)b.y;
}
#endif

__global__ __launch_bounds__(256, 4)
void bilateral_kernel(const float* __restrict__ in,      // [B][32][H][W]
                      const float* __restrict__ guide,   // [B][3][H][W]
                      const float* __restrict__ sigma_p, // [1]
                      float* __restrict__ out)           // [B][32][H][W]
{
    // parity-split layout: site (row,col) -> [(row*2 + (col&1))*PAIRS + (col>>1)]
    // thread (tx) reads per parity pairs tx..tx+3 -> contiguous 16B/8B-stride,
    // conflict-free full-bank-sweep reads with compile-time immediate offsets.
    __shared__ uint4 dt2[HR * 2 * PAIRS];   // input: 8ch fp16 per site
    __shared__ uint2 gt2[HR * 2 * PAIRS];   // guide: {x,y},{z,0} fp16 per site

    const int tid = threadIdx.x;
    const int tx  = tid & 15;            // x-pair index
    const int ty  = tid >> 4;            // y row (0..15)
    const int x0  = blockIdx.x * TW;
    const int y0  = blockIdx.y * TH;
    const int b   = blockIdx.z >> 2;     // batch
    const int cg0 = (blockIdx.z & 3) * 8;

    const float* gb  = guide + (size_t)b * 3 * HWp;
    const float* inb = in    + ((size_t)b * 32 + cg0) * HWp;

    const float sigma = sigma_p[0];
    const float isig2 = 1.0f / (sigma * sigma);
    const float L2E   = 1.442695041f;    // log2(e)
    float lnT2[KS];                       // log2 of spatial factor
#pragma unroll
    for (int i = 0; i < KS; ++i) {
        float r = (float)(i - RAD);
        lnT2[i] = -0.5f * r * r * isig2 * L2E;
    }

    // ---- stage: guide fp16 (uint2) + input 8ch fp16 (uint4), zero halo ----
#pragma unroll
    for (int it = 0; it < 4; ++it) {
        int idx = tid + it * 256;
        if (idx < NT) {
            int row = idx / HC;
            int col = idx - row * HC;
            int gy = y0 - RAD + row, gx = x0 - RAD + col;
            uint2 gv = make_uint2(0u, 0u);
            uint4 pv = make_uint4(0u, 0u, 0u, 0u);
            if (gy >= 0 && gy < H && gx >= 0 && gx < W) {
                int off = gy * W + gx;
                gv.x = pk(gb[off], gb[HWp + off]);
                gv.y = pk(gb[2 * HWp + off], 0.f);
                float v0 = inb[off],           v1 = inb[HWp + off];
                float v2 = inb[2 * HWp + off], v3 = inb[3 * HWp + off];
                float v4 = inb[4 * HWp + off], v5 = inb[5 * HWp + off];
                float v6 = inb[6 * HWp + off], v7 = inb[7 * HWp + off];
                pv.x = pk(v0, v1); pv.y = pk(v2, v3);
                pv.z = pk(v4, v5); pv.w = pk(v6, v7);
            }
            int s = (row * 2 + (col & 1)) * PAIRS + (col >> 1);
            gt2[s] = gv;
            dt2[s] = pv;
        }
    }
    __syncthreads();

    // ---- negated centers: px0 col 2tx+3 (parity1,pair tx+1); px1 col 2tx+4 (parity0,pair tx+2)
    const int cb = (ty + RAD) * 2 * PAIRS;
    uint2 c0r = gt2[cb + PAIRS + tx + 1];
    uint2 c1r = gt2[cb + tx + 2];
    const f16x2 nc0xy = -__builtin_bit_cast(f16x2, c0r.x);
    const f16x2 nc0z  = -__builtin_bit_cast(f16x2, c0r.y);
    const f16x2 nc1xy = -__builtin_bit_cast(f16x2, c1r.x);
    const f16x2 nc1z  = -__builtin_bit_cast(f16x2, c1r.y);

    float n0 = 0.f, n1 = 0.f;
    float a0[8], a1[8];
#pragma unroll
    for (int c = 0; c < 8; ++c) { a0[c] = 0.f; a1[c] = 0.f; }

    // ---- fused weight+apply; fp16 row-accumulate, f32 flush per row ----
#pragma unroll
    for (int i = 0; i < KS; ++i) {
        const int rb = (ty + i) * 2 * PAIRS;   // affine in i: folds into imm offsets
        uint2 gq[8];
        uint4 rq[8];
#pragma unroll
        for (int k = 0; k < 8; ++k) {
            int s = rb + (k & 1) * PAIRS + tx + (k >> 1);  // col 2tx+k
            gq[k] = gt2[s];
            rq[k] = dt2[s];
        }
        f16x2 A0[4], A1[4];
#pragma unroll
        for (int k = 0; k < 4; ++k) { A0[k] = (f16x2)0; A1[k] = (f16x2)0; }
#pragma unroll
        for (int dj = 0; dj < KS; ++dj) {
            const float lnE = lnT2[i] + lnT2[dj];
            // pixel 0: window col 2tx+dj
            f16x2 gxy = __builtin_bit_cast(f16x2, gq[dj].x);
            f16x2 gz  = __builtin_bit_cast(f16x2, gq[dj].y);
            f16x2 dxy = gxy + nc0xy;
            f16x2 dz  = gz + nc0z;           // lane1 = 0
            float s0 = fdot2(dxy, dxy, fdot2(dz, dz, 0.f));
            float w0 = exp2f(fmaf(s0, -0.5f * L2E, lnE));
            n0 += w0;
            f16x2 w0h = pkh(w0, w0);
            A0[0] = w0h * __builtin_bit_cast(f16x2, rq[dj].x) + A0[0];
            A0[1] = w0h * __builtin_bit_cast(f16x2, rq[dj].y) + A0[1];
            A0[2] = w0h * __builtin_bit_cast(f16x2, rq[dj].z) + A0[2];
            A0[3] = w0h * __builtin_bit_cast(f16x2, rq[dj].w) + A0[3];
            // pixel 1: window col 2tx+dj+1
            gxy = __builtin_bit_cast(f16x2, gq[dj + 1].x);
            gz  = __builtin_bit_cast(f16x2, gq[dj + 1].y);
            dxy = gxy + nc1xy;
            dz  = gz + nc1z;
            float s1 = fdot2(dxy, dxy, fdot2(dz, dz, 0.f));
            float w1 = exp2f(fmaf(s1, -0.5f * L2E, lnE));
            n1 += w1;
            f16x2 w1h = pkh(w1, w1);
            A1[0] = w1h * __builtin_bit_cast(f16x2, rq[dj + 1].x) + A1[0];
            A1[1] = w1h * __builtin_bit_cast(f16x2, rq[dj + 1].y) + A1[1];
            A1[2] = w1h * __builtin_bit_cast(f16x2, rq[dj + 1].z) + A1[2];
            A1[3] = w1h * __builtin_bit_cast(f16x2, rq[dj + 1].w) + A1[3];
        }
        // flush row accumulators to f32 (bounds fp16 chain at 7 adds)
#pragma unroll
        for (int k = 0; k < 4; ++k) {
            a0[2 * k]     += (float)A0[k].x;
            a0[2 * k + 1] += (float)A0[k].y;
            a1[2 * k]     += (float)A1[k].x;
            a1[2 * k + 1] += (float)A1[k].y;
        }
    }

    // ---- normalize + store (norm >= center weight = 1, never 0) ----
    const float i0 = 1.f / n0, i1 = 1.f / n1;
    const int X = x0 + 2 * tx, Y = y0 + ty;
    float* ob = out + ((size_t)b * 32 + cg0) * HWp + (size_t)Y * W + X;
#pragma unroll
    for (int c = 0; c < 8; ++c) {
        float2 s;
        s.x = a0[c] * i0;
        s.y = a1[c] * i1;
        *(float2*)(ob + (size_t)c * HWp) = s;
    }
}

extern "C" void kernel_launch(void* const* d_in, const int* in_sizes, int n_in,
                              void* d_out, int out_size, void* d_ws, size_t ws_size,
                              hipStream_t stream) {
    const float* in    = (const float*)d_in[0];
    const float* guide = (const float*)d_in[1];
    const float* sigma = (const float*)d_in[2];
    float* out = (float*)d_out;
    dim3 grid(W / TW, H / TH, 2 * 4);   // z = batch*4 + channel-quarter
    bilateral_kernel<<<grid, dim3(256), 0, stream>>>(in, guide, sigma, out);
}